// Round 8
// baseline (139.670 us; speedup 1.0000x reference)
//
#include <hip/hip_runtime.h>
#include <stdint.h>

#define NPIX 9216   // 96*96
#define NIMG 32
#define STRIP 1152  // NPIX / 8 strips

// ---------- JAX threefry2x32 (20 rounds), bit-exact (verified rounds 1-7) ----------
__device__ __forceinline__ uint32_t rotl32(uint32_t x, int d){ return (x<<d)|(x>>(32-d)); }

__device__ __forceinline__ void threefry(uint32_t k0, uint32_t k1, uint32_t x0, uint32_t x1,
                                         uint32_t &o0, uint32_t &o1){
  uint32_t ks2 = k0 ^ k1 ^ 0x1BD11BDAu;
  x0 += k0; x1 += k1;
  x0+=x1; x1=rotl32(x1,13); x1^=x0;
  x0+=x1; x1=rotl32(x1,15); x1^=x0;
  x0+=x1; x1=rotl32(x1,26); x1^=x0;
  x0+=x1; x1=rotl32(x1,6);  x1^=x0;
  x0+=k1; x1+=ks2+1u;
  x0+=x1; x1=rotl32(x1,17); x1^=x0;
  x0+=x1; x1=rotl32(x1,29); x1^=x0;
  x0+=x1; x1=rotl32(x1,16); x1^=x0;
  x0+=x1; x1=rotl32(x1,24); x1^=x0;
  x0+=ks2; x1+=k0+2u;
  x0+=x1; x1=rotl32(x1,13); x1^=x0;
  x0+=x1; x1=rotl32(x1,15); x1^=x0;
  x0+=x1; x1=rotl32(x1,26); x1^=x0;
  x0+=x1; x1=rotl32(x1,6);  x1^=x0;
  x0+=k0; x1+=k1+3u;
  x0+=x1; x1=rotl32(x1,17); x1^=x0;
  x0+=x1; x1=rotl32(x1,29); x1^=x0;
  x0+=x1; x1=rotl32(x1,16); x1^=x0;
  x0+=x1; x1=rotl32(x1,24); x1^=x0;
  x0+=k1; x1+=ks2+4u;
  x0+=x1; x1=rotl32(x1,13); x1^=x0;
  x0+=x1; x1=rotl32(x1,15); x1^=x0;
  x0+=x1; x1=rotl32(x1,26); x1^=x0;
  x0+=x1; x1=rotl32(x1,6);  x1^=x0;
  x0+=ks2; x1+=k0+5u;
  o0=x0; o1=x1;
}

__device__ __forceinline__ float clip01_div255(float x){
  return fminf(fmaxf(x/255.0f, 0.0f), 1.0f);
}

// ---------- K1: 512 blocks = img x cls x 8 strips.
// Redundant full-image channel max (12-float groups, compile-time channel map),
// score own strip, exact local top-50; LAST block per image (ticket fan-in)
// merges 16 lists + computes stats (R7 kmerge verbatim). ----------
__global__ __launch_bounds__(256) void kscore(const float* __restrict__ in,
                                              unsigned long long* __restrict__ key50g,
                                              int* __restrict__ ticket,
                                              float* __restrict__ ts2g,      // [32][600]
                                              float* __restrict__ meanstd){  // [32][10]
#pragma clang fp contract(off)
  int b   = blockIdx.x;                 // img*16 + cls*8 + sub
  int img = b >> 4, cls = (b >> 3) & 1, sub = b & 7;
  int tid = threadIdx.x;
  int lane = tid & 63, wv = tid >> 6;

  __shared__ __attribute__((aligned(16))) float pixL[3456];  // strip pixels
  __shared__ uint32_t vvL[STRIP];
  __shared__ uint64_t cand[STRIP];      // reused as kk[800] in merge tail
  __shared__ int hist[129];
  __shared__ int ncand, bbin, myold;
  __shared__ float red[3][4];
  __shared__ int   tIdx[100];
  __shared__ float feat[100][5];
  __shared__ float mv[5], sv[5];

  if(tid<129) hist[tid]=0;
  if(tid==0)  ncand=0;

  const float* p = in + (size_t)img*NPIX*3;

  // stage own strip (864 float4, coalesced)
  const float4* sp4 = (const float4*)(p + (size_t)sub*STRIP*3);
  float4* pixL4 = (float4*)pixL;
  for(int k=0;k<4;k++){ int i4=k*256+tid; if(i4<864) pixL4[i4]=sp4[i4]; }

  // redundant full-image channel max: 2304 groups of 3 float4 (= 4 pixels)
  // channel map fixed: v0=(0,1,2,0) v1=(1,2,0,1) v2=(2,0,1,2); fmax exactly assoc.
  float m0=0.f,m1=0.f,m2=0.f;
  const float4* p4 = (const float4*)p;
  for(int g=tid; g<2304; g+=256){
    float4 v0=p4[3*g], v1=p4[3*g+1], v2=p4[3*g+2];
    m0=fmaxf(m0, fmaxf(fmaxf(clip01_div255(v0.x),clip01_div255(v0.w)),
                       fmaxf(clip01_div255(v1.z),clip01_div255(v2.y))));
    m1=fmaxf(m1, fmaxf(fmaxf(clip01_div255(v0.y),clip01_div255(v1.x)),
                       fmaxf(clip01_div255(v1.w),clip01_div255(v2.z))));
    m2=fmaxf(m2, fmaxf(fmaxf(clip01_div255(v0.z),clip01_div255(v1.y)),
                       fmaxf(clip01_div255(v2.x),clip01_div255(v2.w))));
  }
  for(int off=32;off>0;off>>=1){
    m0=fmaxf(m0,__shfl_down(m0,off));
    m1=fmaxf(m1,__shfl_down(m1,off));
    m2=fmaxf(m2,__shfl_down(m2,off));
  }
  if(lane==0){ red[0][wv]=m0; red[1][wv]=m1; red[2][wv]=m2; }
  __syncthreads();
  float c0=fmaxf(fmaxf(red[0][0],red[0][1]),fmaxf(red[0][2],red[0][3]));
  float c1=fmaxf(fmaxf(red[1][0],red[1][1]),fmaxf(red[1][2],red[1][3]));
  float c2=fmaxf(fmaxf(red[2][0],red[2][1]),fmaxf(red[2][2],red[2][3]));

  // partitionable threefry keys (bit-exact)
  uint32_t ik0, ik1; threefry(0u, 42u, 0u, (uint32_t)img, ik0, ik1);
  uint32_t s0, s1;   threefry(ik0, ik1, 0u, (uint32_t)cls, s0, s1);

  // score strip + histogram
  for(int r=0;r<5;r++){
    int pi = tid + r*256;
    if(pi<STRIP){
      float a  = clip01_div255(pixL[pi*3+0])/c0;
      float bb = clip01_div255(pixL[pi*3+1])/c1;
      float c  = clip01_div255(pixL[pi*3+2])/c2;
      bool fg = (a>0.f && a<0.6f) || (bb>0.f && bb<0.6f) || (c>0.f && c<0.6f);
      bool valid = (cls==0) ? fg : !fg;
      uint32_t gi = (uint32_t)(sub*STRIP + pi);
      uint32_t r1,r2; threefry(s0, s1, 0u, gi, r1, r2);
      uint32_t vv = valid ? ((r1 ^ r2) >> 9) + 1u : 0u;  // monotone in uniform; 0 = invalid(-1.0)
      vvL[pi] = vv;
      atomicAdd(&hist[vv>>16], 1);
    }
  }
  __syncthreads();
  if(tid==0){
    int acc=0, bx=128;
    for(; bx>=0; bx--){ acc += hist[bx]; if(acc>=50) break; }
    bbin = bx;                           // strip has 1152 keys -> always reaches 50
  }
  __syncthreads();
  int bb = bbin;
  for(int r=0;r<5;r++){
    int pi = tid + r*256;
    if(pi<STRIP){
      uint32_t vv = vvL[pi];
      if((int)(vv>>16) >= bb){
        int pos = atomicAdd(&ncand,1);
        cand[pos] = ((uint64_t)vv << 14) | (uint64_t)(16383 - (sub*STRIP + pi));  // higher = earlier
      }
    }
  }
  __syncthreads();
  int m = ncand;
  for(int c=tid;c<m;c+=256){
    uint64_t k = cand[c];
    int r = 0, j = 0;
    while(j < m){                        // chunked early-exit: exact for r<50
      int je = j+64 < m ? j+64 : m;
      for(; j<je; j++) r += (cand[j] > k);
      if(r >= 50) break;
    }
    if(r < 50) key50g[(size_t)b*50 + r] = k;  // rank r -> descending sorted list
  }

  // ---- ticket fan-in: last of the 16 blocks per image runs the merge+stats ----
  __threadfence();                       // release this block's key50g writes
  __syncthreads();
  if(tid==0){
    atomicCAS(&ticket[img], (int)0xAAAAAAAA, 0);   // normalize 0xAA poison (or 0)
    myold = atomicAdd(&ticket[img], 1);            // olds are 0..15 in arrival order
  }
  __syncthreads();
  if(myold != 15) return;                // not last -> done

  // last arriver: all 16 blocks' writes are fenced-then-counted -> visible
  __threadfence();                       // acquire
  uint64_t* kk = cand;                   // reuse (1152 >= 800)
  const uint64_t* kg = (const uint64_t*)key50g + (size_t)img*800;
  __syncthreads();                       // cand rank-phase reads done before overwrite
  for(int c=tid;c<800;c+=256) kk[c] = kg[c];
  __syncthreads();

  // global rank within class via binary search on 8 descending 50-lists (keys unique)
  for(int c=tid;c<800;c+=256){
    uint64_t k = kk[c];
    int cl = (c >= 400);
    int base = cl*400;
    int r = 0;
#pragma unroll
    for(int s=0;s<8;s++){
      const uint64_t* L = &kk[base + s*50];
      int lo=0, hi=50;
      while(lo<hi){ int mid=(lo+hi)>>1; if(L[mid] > k) lo=mid+1; else hi=mid; }
      r += lo;
    }
    if(r < 50) tIdx[cl*50+r] = 16383 - (int)(k & 16383u);
  }
  __syncthreads();

  // train features + stats (math bit-identical to rounds 1-7)
  if(tid<100){
    int pp = tIdx[tid];
    int i=pp/96, j=pp-i*96;
    const float* px = in + ((size_t)img*NPIX + pp)*3;
    for(int c=0;c<3;c++){
      float ip=clip01_div255(px[c]);
      feat[tid][c]=ip/255.0f;
    }
    feat[tid][3]=((float)i/96.0f)*100.0f;
    feat[tid][4]=((float)j/96.0f)*100.0f;
  }
  __syncthreads();
  if(tid<5){
    float s=0.f;
    for(int r=0;r<100;r++) s=s+feat[r][tid];
    float mu=s/100.0f; mv[tid]=mu;
    float v=0.f;
    for(int r=0;r<100;r++){ float d=feat[r][tid]-mu; float q=d*d; v=v+q; }
    sv[tid]=sqrtf(v/100.0f);
  }
  __syncthreads();
  // standardize into pair-packed layout: pair p holds rows 2p (f0..4), 2p+1 (f5..9), pad 2
  if(tid<100){
    float r0=(feat[tid][0]-mv[0])/sv[0];
    float r1=(feat[tid][1]-mv[1])/sv[1];
    float r2=(feat[tid][2]-mv[2])/sv[2];
    float r3=(feat[tid][3]-mv[3])/sv[3];
    float r4=(feat[tid][4]-mv[4])/sv[4];
    float* dst = ts2g + img*600 + (tid>>1)*12 + (tid&1)*5;
    dst[0]=r0; dst[1]=r1; dst[2]=r2; dst[3]=r3; dst[4]=r4;
  }
  if(tid<5)       meanstd[img*10+tid]=mv[tid];
  else if(tid<10) meanstd[img*10+tid]=sv[tid-5];
}

// ---------- K2: 1152 blocks = img x 36 chunks: lean 5-NN (d^2 a1/b3, 2 sqrts) ------
__global__ __launch_bounds__(256) void kknn(const float* __restrict__ in,
                                            const float* __restrict__ ts2g,
                                            const float* __restrict__ meanstd,
                                            float* __restrict__ out){
#pragma clang fp contract(off)
  int b     = blockIdx.x;
  int img   = b / 36;
  int chunk = b % 36;
  int tid   = threadIdx.x;

  __shared__ float    mv[5], sv[5];
  __shared__ __attribute__((aligned(16))) float ts2[600];  // pair-packed train rows
  __shared__ __attribute__((aligned(16))) float pix[768];

  if(tid<150) ((float4*)ts2)[tid] = ((const float4*)(ts2g + img*600))[tid];
  if(tid>=192 && tid<197) mv[tid-192]=meanstd[img*10+(tid-192)];
  if(tid>=224 && tid<229) sv[tid-224]=meanstd[img*10+5+(tid-224)];
  {
    const float4* cb4 = (const float4*)(in + ((size_t)img*NPIX + (size_t)chunk*256)*3);
    if(tid<192) ((float4*)pix)[tid] = cb4[tid];
  }
  __syncthreads();

  // test feature for own pixel (bit-identical math)
  int p = chunk*256+tid;
  int i=p/96, j=p-i*96;
  float ip0=clip01_div255(pix[tid*3+0]);
  float ip1=clip01_div255(pix[tid*3+1]);
  float ip2=clip01_div255(pix[tid*3+2]);
  float t0,t1,t2,t3,t4;
  {
    float f0=ip0/255.0f, f1=ip1/255.0f, f2=ip2/255.0f;
    float f3=((float)i/96.0f)*100.0f, f4=((float)j/96.0f)*100.0f;
    t0=(f0-mv[0])/sv[0]; t1=(f1-mv[1])/sv[1]; t2=(f2-mv[2])/sv[2];
    t3=(f3-mv[3])/sv[3]; t4=(f4-mv[4])/sv[4];
  }

  // seg <=> (2nd-smallest fg dist) <= (4th-smallest bg dist); intra-class selection
  // in d^2 (sqrt monotone), sqrt only on finalists; fg wins ties (<=). [R6/R7-verified]
  float a0=1e30f,a1=1e30f;               // fg d^2 smallest two
#pragma unroll 5
  for(int pr=0;pr<25;pr++){
    const float* tp = &ts2[pr*12];
    float4 qa = *(const float4*)(tp);    // r0: f0..f3
    float4 qb = *(const float4*)(tp+4);  // r0f4 | r1: f0..f2
    float2 qc = *(const float2*)(tp+8);  // r1: f3,f4
    {
      float s;
      { float d=t0-qa.x; s=d*d; }
      { float d=t1-qa.y; float w=d*d; s=s+w; }
      { float d=t2-qa.z; float w=d*d; s=s+w; }
      { float d=t3-qa.w; float w=d*d; s=s+w; }
      { float d=t4-qb.x; float w=d*d; s=s+w; }
      bool l0=s<a0,l1=s<a1;
      a1 = l1 ? (l0?a0:s) : a1;
      a0 = l0 ? s : a0;
    }
    {
      float s;
      { float d=t0-qb.y; s=d*d; }
      { float d=t1-qb.z; float w=d*d; s=s+w; }
      { float d=t2-qb.w; float w=d*d; s=s+w; }
      { float d=t3-qc.x; float w=d*d; s=s+w; }
      { float d=t4-qc.y; float w=d*d; s=s+w; }
      bool l0=s<a0,l1=s<a1;
      a1 = l1 ? (l0?a0:s) : a1;
      a0 = l0 ? s : a0;
    }
  }
  float b0=1e30f,b1=1e30f,b2=1e30f,b3=1e30f;   // bg d^2 smallest four
#pragma unroll 5
  for(int pr=25;pr<50;pr++){
    const float* tp = &ts2[pr*12];
    float4 qa = *(const float4*)(tp);
    float4 qb = *(const float4*)(tp+4);
    float2 qc = *(const float2*)(tp+8);
    {
      float s;
      { float d=t0-qa.x; s=d*d; }
      { float d=t1-qa.y; float w=d*d; s=s+w; }
      { float d=t2-qa.z; float w=d*d; s=s+w; }
      { float d=t3-qa.w; float w=d*d; s=s+w; }
      { float d=t4-qb.x; float w=d*d; s=s+w; }
      bool l0=s<b0,l1=s<b1,l2=s<b2,l3=s<b3;
      b3 = l3 ? (l2?b2:s) : b3;
      b2 = l2 ? (l1?b1:s) : b2;
      b1 = l1 ? (l0?b0:s) : b1;
      b0 = l0 ? s : b0;
    }
    {
      float s;
      { float d=t0-qb.y; s=d*d; }
      { float d=t1-qb.z; float w=d*d; s=s+w; }
      { float d=t2-qb.w; float w=d*d; s=s+w; }
      { float d=t3-qc.x; float w=d*d; s=s+w; }
      { float d=t4-qc.y; float w=d*d; s=s+w; }
      bool l0=s<b0,l1=s<b1,l2=s<b2,l3=s<b3;
      b3 = l3 ? (l2?b2:s) : b3;
      b2 = l2 ? (l1?b1:s) : b2;
      b1 = l1 ? (l0?b0:s) : b1;
      b0 = l0 ? s : b0;
    }
  }
  bool seg = sqrtf(a1) <= sqrtf(b3);
  __syncthreads();                       // pix reuse fence
  pix[tid*3+0]=seg?ip0:0.f;
  pix[tid*3+1]=seg?ip1:0.f;
  pix[tid*3+2]=seg?ip2:0.f;
  __syncthreads();
  float4* ob4 = (float4*)(out + ((size_t)img*NPIX + (size_t)chunk*256)*3);
  if(tid<192) ob4[tid] = ((float4*)pix)[tid];
}

extern "C" void kernel_launch(void* const* d_in, const int* in_sizes, int n_in,
                              void* d_out, int out_size, void* d_ws, size_t ws_size,
                              hipStream_t stream) {
  const float* in = (const float*)d_in[0];
  float* out = (float*)d_out;
  unsigned long long* key50g = (unsigned long long*)d_ws;   // 512*50*8 = 204800 B
  int*   ticket  = (int*)((char*)d_ws + 204800);            // 32*4 = 128 B (0xAA poison ok)
  float* ts2g    = (float*)((char*)d_ws + 204928);          // 32*600*4 = 76800 B
  float* meanstd = (float*)((char*)d_ws + 281728);          // 1280 B

  kscore<<<512,  256, 0, stream>>>(in, key50g, ticket, ts2g, meanstd);
  kknn  <<<1152, 256, 0, stream>>>(in, ts2g, meanstd, out);
}

// Round 9
// 133.828 us; speedup vs baseline: 1.0437x; 1.0437x over previous
//
#include <hip/hip_runtime.h>
#include <stdint.h>

#define NPIX 9216   // 96*96
#define NIMG 32
#define STRIP 1152  // NPIX / 8 strips

// ---------- JAX threefry2x32 (20 rounds), bit-exact (verified rounds 1-8) ----------
__device__ __forceinline__ uint32_t rotl32(uint32_t x, int d){ return (x<<d)|(x>>(32-d)); }

__device__ __forceinline__ void threefry(uint32_t k0, uint32_t k1, uint32_t x0, uint32_t x1,
                                         uint32_t &o0, uint32_t &o1){
  uint32_t ks2 = k0 ^ k1 ^ 0x1BD11BDAu;
  x0 += k0; x1 += k1;
  x0+=x1; x1=rotl32(x1,13); x1^=x0;
  x0+=x1; x1=rotl32(x1,15); x1^=x0;
  x0+=x1; x1=rotl32(x1,26); x1^=x0;
  x0+=x1; x1=rotl32(x1,6);  x1^=x0;
  x0+=k1; x1+=ks2+1u;
  x0+=x1; x1=rotl32(x1,17); x1^=x0;
  x0+=x1; x1=rotl32(x1,29); x1^=x0;
  x0+=x1; x1=rotl32(x1,16); x1^=x0;
  x0+=x1; x1=rotl32(x1,24); x1^=x0;
  x0+=ks2; x1+=k0+2u;
  x0+=x1; x1=rotl32(x1,13); x1^=x0;
  x0+=x1; x1=rotl32(x1,15); x1^=x0;
  x0+=x1; x1=rotl32(x1,26); x1^=x0;
  x0+=x1; x1=rotl32(x1,6);  x1^=x0;
  x0+=k0; x1+=k1+3u;
  x0+=x1; x1=rotl32(x1,17); x1^=x0;
  x0+=x1; x1=rotl32(x1,29); x1^=x0;
  x0+=x1; x1=rotl32(x1,16); x1^=x0;
  x0+=x1; x1=rotl32(x1,24); x1^=x0;
  x0+=k1; x1+=ks2+4u;
  x0+=x1; x1=rotl32(x1,13); x1^=x0;
  x0+=x1; x1=rotl32(x1,15); x1^=x0;
  x0+=x1; x1=rotl32(x1,26); x1^=x0;
  x0+=x1; x1=rotl32(x1,6);  x1^=x0;
  x0+=ks2; x1+=k0+5u;
  o0=x0; o1=x1;
}

__device__ __forceinline__ float clip01_div255(float x){
  return fminf(fmaxf(x/255.0f, 0.0f), 1.0f);
}

// ---------- K0: partial channel max, 6 blocks/image (reads image exactly once) -----
__global__ __launch_bounds__(256) void kmax(const float* __restrict__ in,
                                            float* __restrict__ maxpart){
  int img  = blockIdx.x / 6;
  int part = blockIdx.x % 6;
  int tid  = threadIdx.x;
  const float* base = in + (size_t)img*NPIX*3 + (size_t)part*1536*3;
  float m0=0.f, m1=0.f, m2=0.f;
#pragma unroll
  for(int k=0;k<18;k++){
    int g = k*256 + tid;
    float v = clip01_div255(base[g]);
    int c = g % 3;
    m0 = (c==0) ? fmaxf(m0,v) : m0;
    m1 = (c==1) ? fmaxf(m1,v) : m1;
    m2 = (c==2) ? fmaxf(m2,v) : m2;
  }
  for(int off=32; off>0; off>>=1){
    m0 = fmaxf(m0, __shfl_down(m0,off));
    m1 = fmaxf(m1, __shfl_down(m1,off));
    m2 = fmaxf(m2, __shfl_down(m2,off));
  }
  __shared__ float r[3][4];
  int lane = tid & 63, wv = tid >> 6;
  if(lane==0){ r[0][wv]=m0; r[1][wv]=m1; r[2][wv]=m2; }
  __syncthreads();
  if(tid==0){
    maxpart[blockIdx.x*3+0]=fmaxf(fmaxf(r[0][0],r[0][1]),fmaxf(r[0][2],r[0][3]));
    maxpart[blockIdx.x*3+1]=fmaxf(fmaxf(r[1][0],r[1][1]),fmaxf(r[1][2],r[1][3]));
    maxpart[blockIdx.x*3+2]=fmaxf(fmaxf(r[2][0],r[2][1]),fmaxf(r[2][2],r[2][3]));
  }
}

// ---------- K1: 512 blocks = img x cls x 8 strips. Software-pipelined staging
// (threefry computed while global loads in flight), exact local top-50; ticket
// fan-in: last block per image merges 16 lists + stats (R8-verified tail). ----------
__global__ __launch_bounds__(256) void kscore(const float* __restrict__ in,
                                              const float* __restrict__ maxpart,
                                              unsigned long long* __restrict__ key50g,
                                              int* __restrict__ ticket,
                                              float* __restrict__ ts2g,      // [32][600]
                                              float* __restrict__ meanstd){  // [32][10]
#pragma clang fp contract(off)
  int b   = blockIdx.x;                 // img*16 + cls*8 + sub
  int img = b >> 4, cls = (b >> 3) & 1, sub = b & 7;
  int tid = threadIdx.x;

  __shared__ __attribute__((aligned(16))) float pixL[3456];  // strip pixels
  __shared__ uint32_t vvL[STRIP];
  __shared__ uint64_t cand[STRIP];      // reused as kk[800] in merge tail
  __shared__ int hist[129];
  __shared__ int ncand, bbin, myold;
  __shared__ int   tIdx[100];
  __shared__ float feat[100][5];
  __shared__ float mv[5], sv[5];

  if(tid<129) hist[tid]=0;
  if(tid==0)  ncand=0;

  const float* p = in + (size_t)img*NPIX*3;

  // issue staging loads into registers (stay in flight through the threefry below)
  const float4* sp4 = (const float4*)(p + (size_t)sub*STRIP*3);
  float4 st0 = sp4[tid];
  float4 st1 = sp4[256+tid];
  float4 st2 = sp4[512+tid];
  float4 st3 = (tid<96) ? sp4[768+tid] : make_float4(0.f,0.f,0.f,0.f);

  // fold 6 partial maxes (uniform -> scalar loads; fmax exactly associative)
  float c0=0.f,c1=0.f,c2=0.f;
#pragma unroll
  for(int s=0;s<6;s++){
    c0=fmaxf(c0, maxpart[(img*6+s)*3+0]);
    c1=fmaxf(c1, maxpart[(img*6+s)*3+1]);
    c2=fmaxf(c2, maxpart[(img*6+s)*3+2]);
  }

  // partitionable threefry (bit-exact): per-pixel bits computed while loads fly
  uint32_t ik0, ik1; threefry(0u, 42u, 0u, (uint32_t)img, ik0, ik1);
  uint32_t s0, s1;   threefry(ik0, ik1, 0u, (uint32_t)cls, s0, s1);
  uint32_t rng[5];
#pragma unroll
  for(int r=0;r<5;r++){
    int pi = tid + r*256;
    if(pi < STRIP){
      uint32_t r1,r2; threefry(s0, s1, 0u, (uint32_t)(sub*STRIP+pi), r1, r2);
      rng[r] = r1 ^ r2;
    }
  }

  // now commit staged pixels to LDS
  float4* pixL4 = (float4*)pixL;
  pixL4[tid]     = st0;
  pixL4[256+tid] = st1;
  pixL4[512+tid] = st2;
  if(tid<96) pixL4[768+tid] = st3;
  __syncthreads();

  // score strip + histogram (math bit-identical to rounds 6-8)
#pragma unroll
  for(int r=0;r<5;r++){
    int pi = tid + r*256;
    if(pi<STRIP){
      float a  = clip01_div255(pixL[pi*3+0])/c0;
      float bb = clip01_div255(pixL[pi*3+1])/c1;
      float c  = clip01_div255(pixL[pi*3+2])/c2;
      bool fg = (a>0.f && a<0.6f) || (bb>0.f && bb<0.6f) || (c>0.f && c<0.6f);
      bool valid = (cls==0) ? fg : !fg;
      uint32_t vv = valid ? (rng[r] >> 9) + 1u : 0u;   // monotone in uniform; 0 = invalid
      vvL[pi] = vv;
      atomicAdd(&hist[vv>>16], 1);
    }
  }
  __syncthreads();
  if(tid==0){
    int acc=0, bx=128;
    for(; bx>=0; bx--){ acc += hist[bx]; if(acc>=50) break; }
    bbin = bx;                           // strip has 1152 keys -> always reaches 50
  }
  __syncthreads();
  int bb = bbin;
  for(int r=0;r<5;r++){
    int pi = tid + r*256;
    if(pi<STRIP){
      uint32_t vv = vvL[pi];
      if((int)(vv>>16) >= bb){
        int pos = atomicAdd(&ncand,1);
        cand[pos] = ((uint64_t)vv << 14) | (uint64_t)(16383 - (sub*STRIP + pi));  // higher = earlier
      }
    }
  }
  __syncthreads();
  int m = ncand;
  for(int c=tid;c<m;c+=256){
    uint64_t k = cand[c];
    int r = 0, j = 0;
    while(j < m){                        // chunked early-exit: exact for r<50
      int je = j+64 < m ? j+64 : m;
      for(; j<je; j++) r += (cand[j] > k);
      if(r >= 50) break;
    }
    if(r < 50) key50g[(size_t)b*50 + r] = k;  // rank r -> descending sorted list
  }

  // ---- ticket fan-in: last of the 16 blocks per image runs the merge+stats ----
  __threadfence();                       // release this block's key50g writes
  __syncthreads();
  if(tid==0){
    atomicCAS(&ticket[img], (int)0xAAAAAAAA, 0);   // normalize 0xAA poison (or 0)
    myold = atomicAdd(&ticket[img], 1);            // olds are 0..15 in arrival order
  }
  __syncthreads();
  if(myold != 15) return;                // not last -> done

  __threadfence();                       // acquire
  uint64_t* kk = cand;                   // reuse (1152 >= 800)
  const uint64_t* kg = (const uint64_t*)key50g + (size_t)img*800;
  __syncthreads();                       // cand rank-phase reads done before overwrite
  for(int c=tid;c<800;c+=256) kk[c] = kg[c];
  __syncthreads();

  // global rank within class via binary search on 8 descending 50-lists (keys unique)
  for(int c=tid;c<800;c+=256){
    uint64_t k = kk[c];
    int cl = (c >= 400);
    int base = cl*400;
    int r = 0;
#pragma unroll
    for(int s=0;s<8;s++){
      const uint64_t* L = &kk[base + s*50];
      int lo=0, hi=50;
      while(lo<hi){ int mid=(lo+hi)>>1; if(L[mid] > k) lo=mid+1; else hi=mid; }
      r += lo;
    }
    if(r < 50) tIdx[cl*50+r] = 16383 - (int)(k & 16383u);
  }
  __syncthreads();

  // train features + stats (math bit-identical to rounds 1-8)
  if(tid<100){
    int pp = tIdx[tid];
    int i=pp/96, j=pp-i*96;
    const float* px = in + ((size_t)img*NPIX + pp)*3;
    for(int c=0;c<3;c++){
      float ip=clip01_div255(px[c]);
      feat[tid][c]=ip/255.0f;
    }
    feat[tid][3]=((float)i/96.0f)*100.0f;
    feat[tid][4]=((float)j/96.0f)*100.0f;
  }
  __syncthreads();
  if(tid<5){
    float s=0.f;
    for(int r=0;r<100;r++) s=s+feat[r][tid];
    float mu=s/100.0f; mv[tid]=mu;
    float v=0.f;
    for(int r=0;r<100;r++){ float d=feat[r][tid]-mu; float q=d*d; v=v+q; }
    sv[tid]=sqrtf(v/100.0f);
  }
  __syncthreads();
  // pair-packed layout: pair p holds rows 2p (f0..4), 2p+1 (f5..9), pad 2
  if(tid<100){
    float r0=(feat[tid][0]-mv[0])/sv[0];
    float r1=(feat[tid][1]-mv[1])/sv[1];
    float r2=(feat[tid][2]-mv[2])/sv[2];
    float r3=(feat[tid][3]-mv[3])/sv[3];
    float r4=(feat[tid][4]-mv[4])/sv[4];
    float* dst = ts2g + img*600 + (tid>>1)*12 + (tid&1)*5;
    dst[0]=r0; dst[1]=r1; dst[2]=r2; dst[3]=r3; dst[4]=r4;
  }
  if(tid<5)       meanstd[img*10+tid]=mv[tid];
  else if(tid<10) meanstd[img*10+tid]=sv[tid-5];
}

// ---------- K2: 1152 blocks: 5-NN with 4 independent select chains + exact merges --
__global__ __launch_bounds__(256) void kknn(const float* __restrict__ in,
                                            const float* __restrict__ ts2g,
                                            const float* __restrict__ meanstd,
                                            float* __restrict__ out){
#pragma clang fp contract(off)
  int b     = blockIdx.x;
  int img   = b / 36;
  int chunk = b % 36;
  int tid   = threadIdx.x;

  __shared__ float    mv[5], sv[5];
  __shared__ __attribute__((aligned(16))) float ts2[600];  // pair-packed train rows
  __shared__ __attribute__((aligned(16))) float pix[768];

  if(tid<150) ((float4*)ts2)[tid] = ((const float4*)(ts2g + img*600))[tid];
  if(tid>=192 && tid<197) mv[tid-192]=meanstd[img*10+(tid-192)];
  if(tid>=224 && tid<229) sv[tid-224]=meanstd[img*10+5+(tid-224)];
  {
    const float4* cb4 = (const float4*)(in + ((size_t)img*NPIX + (size_t)chunk*256)*3);
    if(tid<192) ((float4*)pix)[tid] = cb4[tid];
  }
  __syncthreads();

  // test feature for own pixel (bit-identical math)
  int p = chunk*256+tid;
  int i=p/96, j=p-i*96;
  float ip0=clip01_div255(pix[tid*3+0]);
  float ip1=clip01_div255(pix[tid*3+1]);
  float ip2=clip01_div255(pix[tid*3+2]);
  float t0,t1,t2,t3,t4;
  {
    float f0=ip0/255.0f, f1=ip1/255.0f, f2=ip2/255.0f;
    float f3=((float)i/96.0f)*100.0f, f4=((float)j/96.0f)*100.0f;
    t0=(f0-mv[0])/sv[0]; t1=(f1-mv[1])/sv[1]; t2=(f2-mv[2])/sv[2];
    t3=(f3-mv[3])/sv[3]; t4=(f4-mv[4])/sv[4];
  }

  // fg rows 0..49: two independent top-2 chains (even row -> E, odd row -> O);
  // per-row d^2 op order identical to rounds 6-8; selection in d^2 (sqrt monotone).
  float aE0=1e30f,aE1=1e30f, aO0=1e30f,aO1=1e30f;
#pragma unroll 5
  for(int pr=0;pr<25;pr++){
    const float* tp = &ts2[pr*12];
    float4 qa = *(const float4*)(tp);    // r0: f0..f3
    float4 qb = *(const float4*)(tp+4);  // r0f4 | r1: f0..f2
    float2 qc = *(const float2*)(tp+8);  // r1: f3,f4
    {
      float s;
      { float d=t0-qa.x; s=d*d; }
      { float d=t1-qa.y; float w=d*d; s=s+w; }
      { float d=t2-qa.z; float w=d*d; s=s+w; }
      { float d=t3-qa.w; float w=d*d; s=s+w; }
      { float d=t4-qb.x; float w=d*d; s=s+w; }
      bool l0=s<aE0,l1=s<aE1;
      aE1 = l1 ? (l0?aE0:s) : aE1;
      aE0 = l0 ? s : aE0;
    }
    {
      float s;
      { float d=t0-qb.y; s=d*d; }
      { float d=t1-qb.z; float w=d*d; s=s+w; }
      { float d=t2-qb.w; float w=d*d; s=s+w; }
      { float d=t3-qc.x; float w=d*d; s=s+w; }
      { float d=t4-qc.y; float w=d*d; s=s+w; }
      bool l0=s<aO0,l1=s<aO1;
      aO1 = l1 ? (l0?aO0:s) : aO1;
      aO0 = l0 ? s : aO0;
    }
  }
  // exact 2nd-smallest of union of two sorted pairs (bitonic split)
  float a1 = fmaxf(fminf(aE0,aO1), fminf(aE1,aO0));

  // bg rows 50..99: two independent top-4 chains
  float bP0=1e30f,bP1=1e30f,bP2=1e30f,bP3=1e30f;
  float bQ0=1e30f,bQ1=1e30f,bQ2=1e30f,bQ3=1e30f;
#pragma unroll 5
  for(int pr=25;pr<50;pr++){
    const float* tp = &ts2[pr*12];
    float4 qa = *(const float4*)(tp);
    float4 qb = *(const float4*)(tp+4);
    float2 qc = *(const float2*)(tp+8);
    {
      float s;
      { float d=t0-qa.x; s=d*d; }
      { float d=t1-qa.y; float w=d*d; s=s+w; }
      { float d=t2-qa.z; float w=d*d; s=s+w; }
      { float d=t3-qa.w; float w=d*d; s=s+w; }
      { float d=t4-qb.x; float w=d*d; s=s+w; }
      bool l0=s<bP0,l1=s<bP1,l2=s<bP2,l3=s<bP3;
      bP3 = l3 ? (l2?bP2:s) : bP3;
      bP2 = l2 ? (l1?bP1:s) : bP2;
      bP1 = l1 ? (l0?bP0:s) : bP1;
      bP0 = l0 ? s : bP0;
    }
    {
      float s;
      { float d=t0-qb.y; s=d*d; }
      { float d=t1-qb.z; float w=d*d; s=s+w; }
      { float d=t2-qb.w; float w=d*d; s=s+w; }
      { float d=t3-qc.x; float w=d*d; s=s+w; }
      { float d=t4-qc.y; float w=d*d; s=s+w; }
      bool l0=s<bQ0,l1=s<bQ1,l2=s<bQ2,l3=s<bQ3;
      bQ3 = l3 ? (l2?bQ2:s) : bQ3;
      bQ2 = l2 ? (l1?bQ1:s) : bQ2;
      bQ1 = l1 ? (l0?bQ0:s) : bQ1;
      bQ0 = l0 ? s : bQ0;
    }
  }
  // exact 4th-smallest of union of two sorted quads (bitonic lower-half merge)
  float l0=fminf(bP0,bQ3), l1=fminf(bP1,bQ2), l2=fminf(bP2,bQ1), l3=fminf(bP3,bQ0);
  float b3 = fmaxf(fmaxf(l0,l1), fmaxf(l2,l3));

  // seg <=> 2nd-smallest fg sqrt-dist <= 4th-smallest bg sqrt-dist (fg wins ties);
  // the two sqrts replicate the reference's sqrt-domain tie semantics [R6/R7-verified]
  bool seg = sqrtf(a1) <= sqrtf(b3);
  __syncthreads();                       // pix reuse fence
  pix[tid*3+0]=seg?ip0:0.f;
  pix[tid*3+1]=seg?ip1:0.f;
  pix[tid*3+2]=seg?ip2:0.f;
  __syncthreads();
  float4* ob4 = (float4*)(out + ((size_t)img*NPIX + (size_t)chunk*256)*3);
  if(tid<192) ob4[tid] = ((float4*)pix)[tid];
}

extern "C" void kernel_launch(void* const* d_in, const int* in_sizes, int n_in,
                              void* d_out, int out_size, void* d_ws, size_t ws_size,
                              hipStream_t stream) {
  const float* in = (const float*)d_in[0];
  float* out = (float*)d_out;
  float* maxpart = (float*)d_ws;                                          // 2304 B
  unsigned long long* key50g = (unsigned long long*)((char*)d_ws + 2304); // 204800 B
  int*   ticket  = (int*)((char*)d_ws + 207104);                          // 128 B
  float* ts2g    = (float*)((char*)d_ws + 207232);                        // 76800 B
  float* meanstd = (float*)((char*)d_ws + 284032);                        // 1280 B

  kmax  <<<192,  256, 0, stream>>>(in, maxpart);
  kscore<<<512,  256, 0, stream>>>(in, maxpart, key50g, ticket, ts2g, meanstd);
  kknn  <<<1152, 256, 0, stream>>>(in, ts2g, meanstd, out);
}